// Round 1
// baseline (465.323 us; speedup 1.0000x reference)
//
#include <hip/hip_runtime.h>

typedef unsigned short u16;
typedef __attribute__((ext_vector_type(8))) short short8;
typedef __attribute__((ext_vector_type(4))) u16 u16x4;
typedef __attribute__((ext_vector_type(4))) float f32x4;

__device__ __forceinline__ u16 f2bf(float f) {
  unsigned u = __float_as_uint(f);
  u += 0x7fffu + ((u >> 16) & 1u);
  return (u16)(u >> 16);
}

// ---------------- transpose + cast weights: out[j*K+k] = in[(row0+k)*ld + j]
__global__ void transpose_cast_kernel(const float* __restrict__ in, int in_ld, int row0,
                                      u16* __restrict__ out, int K, int Nout) {
  int i = blockIdx.x * 256 + threadIdx.x;
  if (i >= K * Nout) return;
  int j = i / K, k = i - j * K;
  out[(size_t)j * K + k] = f2bf(in[(size_t)(row0 + k) * in_ld + j]);
}

// ---------------- LayerNorm: 1 wave per row of 384, 6 elems/lane
__global__ void ln_kernel(const float* __restrict__ in, const float* __restrict__ w,
                          const float* __restrict__ b, u16* __restrict__ out) {
  int row = blockIdx.x, t = threadIdx.x;
  const float* r = in + (size_t)row * 384;
  float v[6];
  float s = 0.f;
#pragma unroll
  for (int i = 0; i < 6; i++) { v[i] = r[t + 64 * i]; s += v[i]; }
#pragma unroll
  for (int off = 32; off > 0; off >>= 1) s += __shfl_xor(s, off);
  float mu = s * (1.f / 384.f);
  float q = 0.f;
#pragma unroll
  for (int i = 0; i < 6; i++) { float d = v[i] - mu; q += d * d; }
#pragma unroll
  for (int off = 32; off > 0; off >>= 1) q += __shfl_xor(q, off);
  float rstd = rsqrtf(q * (1.f / 384.f) + 1e-5f);
#pragma unroll
  for (int i = 0; i < 6; i++) {
    int j = t + 64 * i;
    out[(size_t)row * 384 + j] = f2bf((v[i] - mu) * rstd * w[j] + b[j]);
  }
}

// ---------------- bf16 MFMA GEMM: C[M,N] = A[M,K] * Bt[N,K]^T
// 128x128 tile, 256 thr (4 waves, 2x2), each wave 64x64 = 4x4 frags of 16x16x32.
// MODE 0: f32 out            MODE 1: bf16 out + bias (strided ldc)
// MODE 2: qkv split (q,k bf16 [t,384]; v transposed [b][h][d][n])
// MODE 3: f32 out = acc + bias + res   MODE 4: bf16 out = gelu(acc+bias)
template <int MODE>
__global__ __launch_bounds__(256) void gemm_kernel(
    const u16* __restrict__ A, const u16* __restrict__ Bt,
    int M, int N, int K, int ldc,
    const float* __restrict__ bias, const float* __restrict__ res,
    void* __restrict__ out0, void* __restrict__ out1, void* __restrict__ out2) {
  __shared__ u16 Als[128 * 40];  // pad 32->40 bf16 (80B rows, 16B aligned, 2-way banks = free)
  __shared__ u16 Bls[128 * 40];
  const int MB = M >> 7;
  int mb = blockIdx.x % MB, nb = blockIdx.x / MB;
  int m0 = mb << 7, n0 = nb << 7;
  int tid = threadIdx.x;
  int lane = tid & 63, w = tid >> 6;
  int wm = (w >> 1) << 6, wn = (w & 1) << 6;
  int l15 = lane & 15, l16 = lane >> 4;
  const f32x4 fz = {0.f, 0.f, 0.f, 0.f};
  f32x4 acc[4][4];
#pragma unroll
  for (int i = 0; i < 4; i++)
#pragma unroll
    for (int j = 0; j < 4; j++) acc[i][j] = fz;

  for (int k0 = 0; k0 < K; k0 += 32) {
    __syncthreads();
#pragma unroll
    for (int rr = 0; rr < 2; rr++) {
      int idx = rr * 256 + tid;
      int row = idx >> 2, ch = (idx & 3) * 8;
      *(short8*)&Als[row * 40 + ch] = *(const short8*)&A[(size_t)(m0 + row) * K + k0 + ch];
      *(short8*)&Bls[row * 40 + ch] = *(const short8*)&Bt[(size_t)(n0 + row) * K + k0 + ch];
    }
    __syncthreads();
    short8 af[4], bfr[4];
#pragma unroll
    for (int i = 0; i < 4; i++) {
      af[i]  = *(const short8*)&Als[(wm + i * 16 + l15) * 40 + l16 * 8];
      bfr[i] = *(const short8*)&Bls[(wn + i * 16 + l15) * 40 + l16 * 8];
    }
#pragma unroll
    for (int i = 0; i < 4; i++)
#pragma unroll
      for (int j = 0; j < 4; j++)
        acc[i][j] = __builtin_amdgcn_mfma_f32_16x16x32_bf16(af[i], bfr[j], acc[i][j], 0, 0, 0);
  }

#pragma unroll
  for (int i = 0; i < 4; i++)
#pragma unroll
    for (int j = 0; j < 4; j++)
#pragma unroll
      for (int r = 0; r < 4; r++) {
        int row = m0 + wm + i * 16 + l16 * 4 + r;
        int col = n0 + wn + j * 16 + l15;
        float v = acc[i][j][r];
        if (MODE == 0) {
          ((float*)out0)[(size_t)row * ldc + col] = v;
        } else if (MODE == 1) {
          ((u16*)out0)[(size_t)row * ldc + col] = f2bf(v + bias[col]);
        } else if (MODE == 2) {
          if (col < 384) {
            ((u16*)out0)[(size_t)row * 384 + col] = f2bf(v);
          } else if (col < 768) {
            ((u16*)out1)[(size_t)row * 384 + col - 384] = f2bf(v);
          } else {
            int df = col - 768, hh = df >> 6, dd = df & 63;
            ((u16*)out2)[(((size_t)(row >> 11) * 6 + hh) * 64 + dd) * 2048 + (row & 2047)] = f2bf(v);
          }
        } else if (MODE == 3) {
          ((float*)out0)[(size_t)row * ldc + col] = v + bias[col] + res[(size_t)row * ldc + col];
        } else if (MODE == 4) {
          float u = v + bias[col];
          float g = 0.5f * u * (1.f + erff(u * 0.70710678118f));
          ((u16*)out0)[(size_t)row * ldc + col] = f2bf(g);
        }
      }
}

// ---------------- flash attention: grid = B*H*(N/64); 4 waves, 16 Q-rows per wave
__global__ __launch_bounds__(256) void attn_kernel(const u16* __restrict__ qb,
                                                   const u16* __restrict__ kb,
                                                   const u16* __restrict__ vtb,
                                                   u16* __restrict__ ab) {
  __shared__ u16 Qls[64 * 72];
  __shared__ u16 Kls[64 * 72];
  __shared__ u16 Vls[64 * 72];  // [d][j] (V pre-transposed in global)
  __shared__ u16 Pls[64 * 72];  // per-wave 16-row slices
  int bx = blockIdx.x;
  int q0 = (bx & 31) << 6;
  int h = (bx >> 5) % 6;
  int b = bx / 192;
  int tid = threadIdx.x, lane = tid & 63, w = tid >> 6;
  int l15 = lane & 15, l16 = lane >> 4;

  const size_t qbase = (size_t)(b * 2048 + q0) * 384 + h * 64;
#pragma unroll
  for (int rr = 0; rr < 2; rr++) {
    int idx = rr * 256 + tid;
    int row = idx >> 3, ch = (idx & 7) * 8;
    *(short8*)&Qls[row * 72 + ch] = *(const short8*)&qb[qbase + (size_t)row * 384 + ch];
  }
  __syncthreads();
  short8 aq0 = *(const short8*)&Qls[(w * 16 + l15) * 72 + l16 * 8];
  short8 aq1 = *(const short8*)&Qls[(w * 16 + l15) * 72 + 32 + l16 * 8];

  const f32x4 fz = {0.f, 0.f, 0.f, 0.f};
  f32x4 o[4];
#pragma unroll
  for (int di = 0; di < 4; di++) o[di] = fz;
  float mrow[4] = {-1e30f, -1e30f, -1e30f, -1e30f};
  float lrow[4] = {0.f, 0.f, 0.f, 0.f};

  const size_t kbase = (size_t)b * 2048 * 384 + h * 64;
  const size_t vbase = ((size_t)b * 6 + h) * 64 * 2048;

  for (int j0 = 0; j0 < 2048; j0 += 64) {
    __syncthreads();
#pragma unroll
    for (int rr = 0; rr < 2; rr++) {
      int idx = rr * 256 + tid;
      int row = idx >> 3, ch = (idx & 7) * 8;
      *(short8*)&Kls[row * 72 + ch] = *(const short8*)&kb[kbase + (size_t)(j0 + row) * 384 + ch];
      *(short8*)&Vls[row * 72 + ch] = *(const short8*)&vtb[vbase + (size_t)row * 2048 + j0 + ch];
    }
    __syncthreads();

    f32x4 s[4];
#pragma unroll
    for (int nj = 0; nj < 4; nj++) s[nj] = fz;
#pragma unroll
    for (int nj = 0; nj < 4; nj++) {
      short8 kf0 = *(const short8*)&Kls[(nj * 16 + l15) * 72 + l16 * 8];
      short8 kf1 = *(const short8*)&Kls[(nj * 16 + l15) * 72 + 32 + l16 * 8];
      s[nj] = __builtin_amdgcn_mfma_f32_16x16x32_bf16(aq0, kf0, s[nj], 0, 0, 0);
      s[nj] = __builtin_amdgcn_mfma_f32_16x16x32_bf16(aq1, kf1, s[nj], 0, 0, 0);
    }
#pragma unroll
    for (int nj = 0; nj < 4; nj++)
#pragma unroll
      for (int r = 0; r < 4; r++) s[nj][r] *= 0.125f;

    float alpha[4], psum[4];
#pragma unroll
    for (int r = 0; r < 4; r++) {
      float mx = fmaxf(fmaxf(s[0][r], s[1][r]), fmaxf(s[2][r], s[3][r]));
#pragma unroll
      for (int off = 8; off > 0; off >>= 1) mx = fmaxf(mx, __shfl_xor(mx, off));
      float mn = fmaxf(mrow[r], mx);
      alpha[r] = __expf(mrow[r] - mn);
      mrow[r] = mn;
      psum[r] = 0.f;
    }
#pragma unroll
    for (int nj = 0; nj < 4; nj++)
#pragma unroll
      for (int r = 0; r < 4; r++) {
        float p = __expf(s[nj][r] - mrow[r]);
        psum[r] += p;
        Pls[(w * 16 + l16 * 4 + r) * 72 + 16 * nj + l15] = f2bf(p);
      }
#pragma unroll
    for (int r = 0; r < 4; r++) {
#pragma unroll
      for (int off = 8; off > 0; off >>= 1) psum[r] += __shfl_xor(psum[r], off);
      lrow[r] = lrow[r] * alpha[r] + psum[r];
    }
#pragma unroll
    for (int di = 0; di < 4; di++)
#pragma unroll
      for (int r = 0; r < 4; r++) o[di][r] *= alpha[r];

#pragma unroll
    for (int ks = 0; ks < 2; ks++) {
      short8 pa = *(const short8*)&Pls[(w * 16 + l15) * 72 + ks * 32 + l16 * 8];
#pragma unroll
      for (int di = 0; di < 4; di++) {
        short8 vf = *(const short8*)&Vls[(di * 16 + l15) * 72 + ks * 32 + l16 * 8];
        o[di] = __builtin_amdgcn_mfma_f32_16x16x32_bf16(pa, vf, o[di], 0, 0, 0);
      }
    }
  }

#pragma unroll
  for (int r = 0; r < 4; r++) {
    float inv = 1.f / lrow[r];
    int token = b * 2048 + q0 + w * 16 + l16 * 4 + r;
#pragma unroll
    for (int di = 0; di < 4; di++)
      ab[(size_t)token * 384 + h * 64 + di * 16 + l15] = f2bf(o[di][r] * inv);
  }
}

// ---------------- KNN: u = G[idx] + (H[n]-G[n]+b); max over 8; leaky; -> cat[:,384:768]
__global__ void knn_kernel(const float* __restrict__ GH, const int* __restrict__ kidx,
                           const float* __restrict__ kbias, u16* __restrict__ cat) {
  int f = blockIdx.x * 256 + threadIdx.x;
  if (f >= 16384 * 96) return;
  int token = f / 96, j4 = f - token * 96;
  int b = token >> 11, n = token & 2047;
  int j = j4 * 4;
  float4 gs = *(const float4*)&GH[(size_t)token * 768 + j];
  float4 hs = *(const float4*)&GH[(size_t)token * 768 + 384 + j];
  float4 kb4 = *(const float4*)&kbias[j];
  float dx = hs.x - gs.x + kb4.x, dy = hs.y - gs.y + kb4.y;
  float dz = hs.z - gs.z + kb4.z, dw = hs.w - gs.w + kb4.w;
  float mx = -1e30f, my = -1e30f, mz = -1e30f, mw = -1e30f;
#pragma unroll
  for (int k = 0; k < 8; k++) {
    int t = kidx[(b * 8 + k) * 2048 + n];
    float4 g = *(const float4*)&GH[(size_t)t * 768 + j];
    mx = fmaxf(mx, g.x + dx);
    my = fmaxf(my, g.y + dy);
    mz = fmaxf(mz, g.z + dz);
    mw = fmaxf(mw, g.w + dw);
  }
  mx = mx > 0.f ? mx : 0.2f * mx;
  my = my > 0.f ? my : 0.2f * my;
  mz = mz > 0.f ? mz : 0.2f * mz;
  mw = mw > 0.f ? mw : 0.2f * mw;
  u16x4 pk = {f2bf(mx), f2bf(my), f2bf(mz), f2bf(mw)};
  *(u16x4*)&cat[(size_t)token * 768 + 384 + j] = pk;
}

// ---------------- launch
extern "C" void kernel_launch(void* const* d_in, const int* in_sizes, int n_in,
                              void* d_out, int out_size, void* d_ws, size_t ws_size,
                              hipStream_t stream) {
  const float* x       = (const float*)d_in[0];
  const int*   kidx    = (const int*)d_in[1];
  const float* n1w     = (const float*)d_in[2];
  const float* n1b     = (const float*)d_in[3];
  const float* qkv_w   = (const float*)d_in[4];
  const float* proj_w  = (const float*)d_in[5];
  const float* proj_b  = (const float*)d_in[6];
  const float* knn_w   = (const float*)d_in[7];
  const float* knn_b   = (const float*)d_in[8];
  const float* merge_w = (const float*)d_in[9];
  const float* merge_b = (const float*)d_in[10];
  const float* n2w     = (const float*)d_in[11];
  const float* n2b     = (const float*)d_in[12];
  const float* fc1_w   = (const float*)d_in[13];
  const float* fc1_b   = (const float*)d_in[14];
  const float* fc2_w   = (const float*)d_in[15];
  const float* fc2_b   = (const float*)d_in[16];
  float* out = (float*)d_out;
  char* ws = (char*)d_ws;

  // ws layout (bytes) — with reuse, total 130,547,712
  u16* wqkv   = (u16*)(ws + 0);          // 1152x384 bf16
  u16* wproj  = (u16*)(ws + 884736);     // 384x384
  u16* wknn   = (u16*)(ws + 1179648);    // 768x384 (W1t | W2t)
  u16* wmerge = (u16*)(ws + 1769472);    // 384x768
  u16* wfc1   = (u16*)(ws + 2359296);    // 1536x384
  u16* wfc2   = (u16*)(ws + 3538944);    // 384x1536
  u16* nx     = (u16*)(ws + 4718592);    // norm_x bf16; later attn-out
  u16* qbf    = (u16*)(ws + 17301504);   // q; later norm2 out
  u16* kbf    = (u16*)(ws + 29884416);   // k; later cat[:, :] (spans k+vT)
  u16* vtb    = (u16*)(ws + 42467328);   // v transposed [b][h][d][n]
  float* GH   = (float*)(ws + 55050240); // [16384][768] f32; later h bf16
  float* xmid = (float*)(ws + 105381888);
  u16* cat = kbf;
  u16* n2  = qbf;
  u16* abf = nx;
  u16* hbf = (u16*)GH;

  // weight transposes (tiny)
  transpose_cast_kernel<<<(384 * 1152 + 255) / 256, 256, 0, stream>>>(qkv_w, 1152, 0, wqkv, 384, 1152);
  transpose_cast_kernel<<<(384 * 384 + 255) / 256, 256, 0, stream>>>(proj_w, 384, 0, wproj, 384, 384);
  transpose_cast_kernel<<<(384 * 384 + 255) / 256, 256, 0, stream>>>(knn_w, 384, 0, wknn, 384, 384);
  transpose_cast_kernel<<<(384 * 384 + 255) / 256, 256, 0, stream>>>(knn_w, 384, 384, wknn + 384 * 384, 384, 384);
  transpose_cast_kernel<<<(768 * 384 + 255) / 256, 256, 0, stream>>>(merge_w, 384, 0, wmerge, 768, 384);
  transpose_cast_kernel<<<(384 * 1536 + 255) / 256, 256, 0, stream>>>(fc1_w, 1536, 0, wfc1, 384, 1536);
  transpose_cast_kernel<<<(1536 * 384 + 255) / 256, 256, 0, stream>>>(fc2_w, 384, 0, wfc2, 1536, 384);

  // LN1
  ln_kernel<<<16384, 64, 0, stream>>>(x, n1w, n1b, nx);
  // qkv (split epilogue, v transposed)
  gemm_kernel<2><<<128 * 9, 256, 0, stream>>>(nx, wqkv, 16384, 1152, 384, 0, nullptr, nullptr, qbf, kbf, vtb);
  // GH = norm_x @ [W1|W2]
  gemm_kernel<0><<<128 * 6, 256, 0, stream>>>(nx, wknn, 16384, 768, 384, 768, nullptr, nullptr, GH, nullptr, nullptr);
  // attention -> abf (reuses nx space AFTER nx consumed)
  attn_kernel<<<1536, 256, 0, stream>>>(qbf, kbf, vtb, abf);
  // knn gather+max -> cat cols 384:768 (reuses k/v space AFTER attention)
  knn_kernel<<<6144, 256, 0, stream>>>(GH, kidx, knn_b, cat);
  // proj -> cat cols 0:384
  gemm_kernel<1><<<128 * 3, 256, 0, stream>>>(abf, wproj, 16384, 384, 384, 768, proj_b, nullptr, cat, nullptr, nullptr);
  // merge + residual -> xmid
  gemm_kernel<3><<<128 * 3, 256, 0, stream>>>(cat, wmerge, 16384, 384, 768, 384, merge_b, x, xmid, nullptr, nullptr);
  // LN2
  ln_kernel<<<16384, 64, 0, stream>>>(xmid, n2w, n2b, n2);
  // fc1 + gelu -> h (reuses GH space)
  gemm_kernel<4><<<128 * 12, 256, 0, stream>>>(n2, wfc1, 16384, 1536, 384, 1536, fc1_b, nullptr, hbf, nullptr, nullptr);
  // fc2 + residual -> out
  gemm_kernel<3><<<128 * 3, 256, 0, stream>>>(hbf, wfc2, 16384, 384, 1536, 384, fc2_b, xmid, out, nullptr, nullptr);
}

// Round 3
// 387.006 us; speedup vs baseline: 1.2024x; 1.2024x over previous
//
#include <hip/hip_runtime.h>

typedef unsigned short u16;
typedef unsigned int u32;
typedef __attribute__((ext_vector_type(8))) short short8;
typedef __attribute__((ext_vector_type(4))) u16 u16x4;
typedef __attribute__((ext_vector_type(2))) u32 u32x2;
typedef __attribute__((ext_vector_type(4))) float f32x4;

__device__ __forceinline__ u16 f2bf(float f) {
  unsigned u = __float_as_uint(f);
  u += 0x7fffu + ((u >> 16) & 1u);
  return (u16)(u >> 16);
}

// ---------------- transpose + cast weights: out[j*K+k] = in[(row0+k)*ld + j]
__global__ void transpose_cast_kernel(const float* __restrict__ in, int in_ld, int row0,
                                      u16* __restrict__ out, int K, int Nout) {
  int i = blockIdx.x * 256 + threadIdx.x;
  if (i >= K * Nout) return;
  int j = i / K, k = i - j * K;
  out[(size_t)j * K + k] = f2bf(in[(size_t)(row0 + k) * in_ld + j]);
}

// ---------------- LayerNorm: 1 wave per row of 384, 6 elems/lane
__global__ void ln_kernel(const float* __restrict__ in, const float* __restrict__ w,
                          const float* __restrict__ b, u16* __restrict__ out) {
  int row = blockIdx.x, t = threadIdx.x;
  const float* r = in + (size_t)row * 384;
  float v[6];
  float s = 0.f;
#pragma unroll
  for (int i = 0; i < 6; i++) { v[i] = r[t + 64 * i]; s += v[i]; }
#pragma unroll
  for (int off = 32; off > 0; off >>= 1) s += __shfl_xor(s, off);
  float mu = s * (1.f / 384.f);
  float q = 0.f;
#pragma unroll
  for (int i = 0; i < 6; i++) { float d = v[i] - mu; q += d * d; }
#pragma unroll
  for (int off = 32; off > 0; off >>= 1) q += __shfl_xor(q, off);
  float rstd = rsqrtf(q * (1.f / 384.f) + 1e-5f);
#pragma unroll
  for (int i = 0; i < 6; i++) {
    int j = t + 64 * i;
    out[(size_t)row * 384 + j] = f2bf((v[i] - mu) * rstd * w[j] + b[j]);
  }
}

// ---------------- bf16 MFMA GEMM: C[M,N] = A[M,K] * Bt[N,K]^T
// 128x128 tile, 256 thr (4 waves, 2x2), each wave 64x64 = 4x4 frags of 16x16x32.
// MODE 0: f32 out            MODE 1: bf16 out + bias (strided ldc)
// MODE 2: qkv split (q scaled by 0.125*log2e, k bf16 [t,384]; v transposed [b][h][d][n])
// MODE 3: f32 out = acc + bias + res   MODE 4: bf16 out = gelu(acc+bias)
template <int MODE>
__global__ __launch_bounds__(256) void gemm_kernel(
    const u16* __restrict__ A, const u16* __restrict__ Bt,
    int M, int N, int K, int ldc,
    const float* __restrict__ bias, const float* __restrict__ res,
    void* __restrict__ out0, void* __restrict__ out1, void* __restrict__ out2) {
  __shared__ u16 Als[128 * 40];  // pad 32->40 bf16 (80B rows, 16B aligned, 2-way banks = free)
  __shared__ u16 Bls[128 * 40];
  const int MB = M >> 7;
  int mb = blockIdx.x % MB, nb = blockIdx.x / MB;
  int m0 = mb << 7, n0 = nb << 7;
  int tid = threadIdx.x;
  int lane = tid & 63, w = tid >> 6;
  int wm = (w >> 1) << 6, wn = (w & 1) << 6;
  int l15 = lane & 15, l16 = lane >> 4;
  const f32x4 fz = {0.f, 0.f, 0.f, 0.f};
  f32x4 acc[4][4];
#pragma unroll
  for (int i = 0; i < 4; i++)
#pragma unroll
    for (int j = 0; j < 4; j++) acc[i][j] = fz;

  for (int k0 = 0; k0 < K; k0 += 32) {
    __syncthreads();
#pragma unroll
    for (int rr = 0; rr < 2; rr++) {
      int idx = rr * 256 + tid;
      int row = idx >> 2, ch = (idx & 3) * 8;
      *(short8*)&Als[row * 40 + ch] = *(const short8*)&A[(size_t)(m0 + row) * K + k0 + ch];
      *(short8*)&Bls[row * 40 + ch] = *(const short8*)&Bt[(size_t)(n0 + row) * K + k0 + ch];
    }
    __syncthreads();
    short8 af[4], bfr[4];
#pragma unroll
    for (int i = 0; i < 4; i++) {
      af[i]  = *(const short8*)&Als[(wm + i * 16 + l15) * 40 + l16 * 8];
      bfr[i] = *(const short8*)&Bls[(wn + i * 16 + l15) * 40 + l16 * 8];
    }
#pragma unroll
    for (int i = 0; i < 4; i++)
#pragma unroll
      for (int j = 0; j < 4; j++)
        acc[i][j] = __builtin_amdgcn_mfma_f32_16x16x32_bf16(af[i], bfr[j], acc[i][j], 0, 0, 0);
  }

#pragma unroll
  for (int i = 0; i < 4; i++)
#pragma unroll
    for (int j = 0; j < 4; j++)
#pragma unroll
      for (int r = 0; r < 4; r++) {
        int row = m0 + wm + i * 16 + l16 * 4 + r;
        int col = n0 + wn + j * 16 + l15;
        float v = acc[i][j][r];
        if (MODE == 0) {
          ((float*)out0)[(size_t)row * ldc + col] = v;
        } else if (MODE == 1) {
          ((u16*)out0)[(size_t)row * ldc + col] = f2bf(v + bias[col]);
        } else if (MODE == 2) {
          if (col < 384) {
            ((u16*)out0)[(size_t)row * 384 + col] = f2bf(v * 0.18033688011112042f);
          } else if (col < 768) {
            ((u16*)out1)[(size_t)row * 384 + col - 384] = f2bf(v);
          } else {
            int df = col - 768, hh = df >> 6, dd = df & 63;
            ((u16*)out2)[(((size_t)(row >> 11) * 6 + hh) * 64 + dd) * 2048 + (row & 2047)] = f2bf(v);
          }
        } else if (MODE == 3) {
          ((float*)out0)[(size_t)row * ldc + col] = v + bias[col] + res[(size_t)row * ldc + col];
        } else if (MODE == 4) {
          float u = v + bias[col];
          float g = 0.5f * u * (1.f + erff(u * 0.70710678118f));
          ((u16*)out0)[(size_t)row * ldc + col] = f2bf(g);
        }
      }
}

// ---------------- flash attention v2: swapped QK^T (q lane-local), O^T accumulation
// grid = B*H*(N/64); 4 waves, 16 q per wave (q = l15), 64-key tiles
__global__ __launch_bounds__(256) void attn_kernel(const u16* __restrict__ qb,
                                                   const u16* __restrict__ kb,
                                                   const u16* __restrict__ vtb,
                                                   u16* __restrict__ ab) {
  __shared__ u16 Kls[64 * 72];
  __shared__ u16 Vls[64 * 72];   // [d][j] (V pre-transposed in global)
  __shared__ u16 Pls[64 * 72];   // P[q][key], per-wave 16-row slices
  int bx = blockIdx.x;
  int q0 = (bx & 31) << 6;
  int h = (bx >> 5) % 6;
  int b = bx / 192;
  int tid = threadIdx.x, lane = tid & 63, w = tid >> 6;
  int l15 = lane & 15, l16 = lane >> 4;

  // stage Q through Kls (freed before first K tile by the loop's first barrier)
  const size_t qbase = (size_t)(b * 2048 + q0) * 384 + h * 64;
  {
    int idx0 = tid, idx1 = 256 + tid;
    *(short8*)&Kls[(idx0 >> 3) * 72 + (idx0 & 7) * 8] =
        *(const short8*)&qb[qbase + (size_t)(idx0 >> 3) * 384 + (idx0 & 7) * 8];
    *(short8*)&Kls[(idx1 >> 3) * 72 + (idx1 & 7) * 8] =
        *(const short8*)&qb[qbase + (size_t)(idx1 >> 3) * 384 + (idx1 & 7) * 8];
  }
  __syncthreads();
  short8 aq0 = *(const short8*)&Kls[(w * 16 + l15) * 72 + l16 * 8];
  short8 aq1 = *(const short8*)&Kls[(w * 16 + l15) * 72 + 32 + l16 * 8];

  const f32x4 fz = {0.f, 0.f, 0.f, 0.f};
  f32x4 ot[4];  // O^T: lane q = l15; d = di*16 + l16*4 + r
#pragma unroll
  for (int di = 0; di < 4; di++) ot[di] = fz;
  float m = -1e30f, lsum = 0.f;

  const size_t kbase = (size_t)b * 2048 * 384 + h * 64;
  const size_t vbase = ((size_t)b * 6 + h) * 64 * 2048;
  // staging: 64 rows x 64 cols = 512 short8 slots; 256 threads -> 2 slots each
  const int srow = tid >> 3, sch = (tid & 7) * 8;  // rows srow and srow+32

  // T14-lite: preload tile 0 into regs
  short8 kr0 = *(const short8*)&kb[kbase + (size_t)srow * 384 + sch];
  short8 kr1 = *(const short8*)&kb[kbase + (size_t)(srow + 32) * 384 + sch];
  short8 vr0 = *(const short8*)&vtb[vbase + (size_t)srow * 2048 + sch];
  short8 vr1 = *(const short8*)&vtb[vbase + (size_t)(srow + 32) * 2048 + sch];

  for (int t = 0; t < 32; t++) {
    __syncthreads();  // previous tile's LDS reads done (and Q-staging consumed)
    *(short8*)&Kls[srow * 72 + sch] = kr0;
    *(short8*)&Kls[(srow + 32) * 72 + sch] = kr1;
    *(short8*)&Vls[srow * 72 + sch] = vr0;
    *(short8*)&Vls[(srow + 32) * 72 + sch] = vr1;
    if (t + 1 < 32) {  // issue next tile's loads; they fly during compute below
      int j0n = (t + 1) << 6;
      kr0 = *(const short8*)&kb[kbase + (size_t)(j0n + srow) * 384 + sch];
      kr1 = *(const short8*)&kb[kbase + (size_t)(j0n + srow + 32) * 384 + sch];
      vr0 = *(const short8*)&vtb[vbase + (size_t)srow * 2048 + j0n + sch];
      vr1 = *(const short8*)&vtb[vbase + (size_t)(srow + 32) * 2048 + j0n + sch];
    }
    __syncthreads();

    // S^T = K·Q^T : mfma(A=K_frag, B=Q_frag) -> col=q=l15, row=key
    f32x4 s[4];
#pragma unroll
    for (int nj = 0; nj < 4; nj++) {
      short8 kf0 = *(const short8*)&Kls[(nj * 16 + l15) * 72 + l16 * 8];
      short8 kf1 = *(const short8*)&Kls[(nj * 16 + l15) * 72 + 32 + l16 * 8];
      s[nj] = __builtin_amdgcn_mfma_f32_16x16x32_bf16(kf0, aq0, fz, 0, 0, 0);
      s[nj] = __builtin_amdgcn_mfma_f32_16x16x32_bf16(kf1, aq1, s[nj], 0, 0, 0);
    }

    // per-lane softmax over the lane's 16 keys, then reduce across l16 groups
    float a0 = fmaxf(fmaxf(s[0][0], s[0][1]), fmaxf(s[0][2], s[0][3]));
    float a1 = fmaxf(fmaxf(s[1][0], s[1][1]), fmaxf(s[1][2], s[1][3]));
    float a2 = fmaxf(fmaxf(s[2][0], s[2][1]), fmaxf(s[2][2], s[2][3]));
    float a3 = fmaxf(fmaxf(s[3][0], s[3][1]), fmaxf(s[3][2], s[3][3]));
    float mt = fmaxf(fmaxf(a0, a1), fmaxf(a2, a3));
    mt = fmaxf(mt, __shfl_xor(mt, 16));
    mt = fmaxf(mt, __shfl_xor(mt, 32));
    float mn = fmaxf(m, mt);
    float alpha = exp2f(m - mn);
    m = mn;

    float ps = 0.f;
#pragma unroll
    for (int nj = 0; nj < 4; nj++) {
      float p0 = exp2f(s[nj][0] - m);
      float p1 = exp2f(s[nj][1] - m);
      float p2 = exp2f(s[nj][2] - m);
      float p3 = exp2f(s[nj][3] - m);
      ps += (p0 + p1) + (p2 + p3);
      // truncate-pack to bf16 pairs (p in (0,1], trunc err < 0.4% rel)
      u32 lo = (__float_as_uint(p1) & 0xffff0000u) | (__float_as_uint(p0) >> 16);
      u32 hi = (__float_as_uint(p3) & 0xffff0000u) | (__float_as_uint(p2) >> 16);
      u32x2 pr = {lo, hi};
      *(u32x2*)&Pls[(w * 16 + l15) * 72 + nj * 16 + l16 * 4] = pr;
    }
    ps += __shfl_xor(ps, 16);
    ps += __shfl_xor(ps, 32);
    lsum = lsum * alpha + ps;

#pragma unroll
    for (int di = 0; di < 4; di++)
#pragma unroll
      for (int r = 0; r < 4; r++) ot[di][r] *= alpha;

    // O^T += V^T · P^T : mfma(A=V^T_frag, B=P^T_frag) -> col=q=l15, row=d
#pragma unroll
    for (int ks = 0; ks < 2; ks++) {
      short8 pb = *(const short8*)&Pls[(w * 16 + l15) * 72 + ks * 32 + l16 * 8];
#pragma unroll
      for (int di = 0; di < 4; di++) {
        short8 vf = *(const short8*)&Vls[(di * 16 + l15) * 72 + ks * 32 + l16 * 8];
        ot[di] = __builtin_amdgcn_mfma_f32_16x16x32_bf16(vf, pb, ot[di], 0, 0, 0);
      }
    }
  }

  float inv = 1.f / lsum;
  int token = b * 2048 + q0 + w * 16 + l15;
#pragma unroll
  for (int di = 0; di < 4; di++) {
    u16x4 pk4 = {f2bf(ot[di][0] * inv), f2bf(ot[di][1] * inv),
                 f2bf(ot[di][2] * inv), f2bf(ot[di][3] * inv)};
    *(u16x4*)&ab[(size_t)token * 384 + h * 64 + di * 16 + l16 * 4] = pk4;
  }
}

// ---------------- KNN: u = G[idx] + (H[n]-G[n]+b); max over 8; leaky; -> cat[:,384:768]
__global__ void knn_kernel(const float* __restrict__ GH, const int* __restrict__ kidx,
                           const float* __restrict__ kbias, u16* __restrict__ cat) {
  int f = blockIdx.x * 256 + threadIdx.x;
  if (f >= 16384 * 96) return;
  int token = f / 96, j4 = f - token * 96;
  int b = token >> 11, n = token & 2047;
  int j = j4 * 4;
  float4 gs = *(const float4*)&GH[(size_t)token * 768 + j];
  float4 hs = *(const float4*)&GH[(size_t)token * 768 + 384 + j];
  float4 kb4 = *(const float4*)&kbias[j];
  float dx = hs.x - gs.x + kb4.x, dy = hs.y - gs.y + kb4.y;
  float dz = hs.z - gs.z + kb4.z, dw = hs.w - gs.w + kb4.w;
  float mx = -1e30f, my = -1e30f, mz = -1e30f, mw = -1e30f;
#pragma unroll
  for (int k = 0; k < 8; k++) {
    int t = kidx[(b * 8 + k) * 2048 + n];
    float4 g = *(const float4*)&GH[(size_t)t * 768 + j];
    mx = fmaxf(mx, g.x + dx);
    my = fmaxf(my, g.y + dy);
    mz = fmaxf(mz, g.z + dz);
    mw = fmaxf(mw, g.w + dw);
  }
  mx = mx > 0.f ? mx : 0.2f * mx;
  my = my > 0.f ? my : 0.2f * my;
  mz = mz > 0.f ? mz : 0.2f * mz;
  mw = mw > 0.f ? mw : 0.2f * mw;
  u16x4 pk = {f2bf(mx), f2bf(my), f2bf(mz), f2bf(mw)};
  *(u16x4*)&cat[(size_t)token * 768 + 384 + j] = pk;
}

// ---------------- launch
extern "C" void kernel_launch(void* const* d_in, const int* in_sizes, int n_in,
                              void* d_out, int out_size, void* d_ws, size_t ws_size,
                              hipStream_t stream) {
  const float* x       = (const float*)d_in[0];
  const int*   kidx    = (const int*)d_in[1];
  const float* n1w     = (const float*)d_in[2];
  const float* n1b     = (const float*)d_in[3];
  const float* qkv_w   = (const float*)d_in[4];
  const float* proj_w  = (const float*)d_in[5];
  const float* proj_b  = (const float*)d_in[6];
  const float* knn_w   = (const float*)d_in[7];
  const float* knn_b   = (const float*)d_in[8];
  const float* merge_w = (const float*)d_in[9];
  const float* merge_b = (const float*)d_in[10];
  const float* n2w     = (const float*)d_in[11];
  const float* n2b     = (const float*)d_in[12];
  const float* fc1_w   = (const float*)d_in[13];
  const float* fc1_b   = (const float*)d_in[14];
  const float* fc2_w   = (const float*)d_in[15];
  const float* fc2_b   = (const float*)d_in[16];
  float* out = (float*)d_out;
  char* ws = (char*)d_ws;

  // ws layout (bytes) — with reuse, total ~130.5 MB
  u16* wqkv   = (u16*)(ws + 0);          // 1152x384 bf16
  u16* wproj  = (u16*)(ws + 884736);     // 384x384
  u16* wknn   = (u16*)(ws + 1179648);    // 768x384 (W1t | W2t)
  u16* wmerge = (u16*)(ws + 1769472);    // 384x768
  u16* wfc1   = (u16*)(ws + 2359296);    // 1536x384
  u16* wfc2   = (u16*)(ws + 3538944);    // 384x1536
  u16* nx     = (u16*)(ws + 4718592);    // norm_x bf16; later attn-out
  u16* qbf    = (u16*)(ws + 17301504);   // q (pre-scaled); later norm2 out
  u16* kbf    = (u16*)(ws + 29884416);   // k; later cat (spans k+vT)
  u16* vtb    = (u16*)(ws + 42467328);   // v transposed [b][h][d][n]
  float* GH   = (float*)(ws + 55050240); // [16384][768] f32; later h bf16
  float* xmid = (float*)(ws + 105381888);
  u16* cat = kbf;
  u16* n2  = qbf;
  u16* abf = nx;
  u16* hbf = (u16*)GH;

  // weight transposes (tiny)
  transpose_cast_kernel<<<(384 * 1152 + 255) / 256, 256, 0, stream>>>(qkv_w, 1152, 0, wqkv, 384, 1152);
  transpose_cast_kernel<<<(384 * 384 + 255) / 256, 256, 0, stream>>>(proj_w, 384, 0, wproj, 384, 384);
  transpose_cast_kernel<<<(384 * 384 + 255) / 256, 256, 0, stream>>>(knn_w, 384, 0, wknn, 384, 384);
  transpose_cast_kernel<<<(384 * 384 + 255) / 256, 256, 0, stream>>>(knn_w, 384, 384, wknn + 384 * 384, 384, 384);
  transpose_cast_kernel<<<(768 * 384 + 255) / 256, 256, 0, stream>>>(merge_w, 384, 0, wmerge, 768, 384);
  transpose_cast_kernel<<<(384 * 1536 + 255) / 256, 256, 0, stream>>>(fc1_w, 1536, 0, wfc1, 384, 1536);
  transpose_cast_kernel<<<(1536 * 384 + 255) / 256, 256, 0, stream>>>(fc2_w, 384, 0, wfc2, 1536, 384);

  // LN1
  ln_kernel<<<16384, 64, 0, stream>>>(x, n1w, n1b, nx);
  // qkv (split epilogue, q pre-scaled, v transposed)
  gemm_kernel<2><<<128 * 9, 256, 0, stream>>>(nx, wqkv, 16384, 1152, 384, 0, nullptr, nullptr, qbf, kbf, vtb);
  // GH = norm_x @ [W1|W2]
  gemm_kernel<0><<<128 * 6, 256, 0, stream>>>(nx, wknn, 16384, 768, 384, 768, nullptr, nullptr, GH, nullptr, nullptr);
  // attention -> abf (reuses nx space AFTER nx consumed)
  attn_kernel<<<1536, 256, 0, stream>>>(qbf, kbf, vtb, abf);
  // knn gather+max -> cat cols 384:768 (reuses k/v space AFTER attention)
  knn_kernel<<<6144, 256, 0, stream>>>(GH, kidx, knn_b, cat);
  // proj -> cat cols 0:384
  gemm_kernel<1><<<128 * 3, 256, 0, stream>>>(abf, wproj, 16384, 384, 384, 768, proj_b, nullptr, cat, nullptr, nullptr);
  // merge + residual -> xmid
  gemm_kernel<3><<<128 * 3, 256, 0, stream>>>(cat, wmerge, 16384, 384, 768, 384, merge_b, x, xmid, nullptr, nullptr);
  // LN2
  ln_kernel<<<16384, 64, 0, stream>>>(xmid, n2w, n2b, n2);
  // fc1 + gelu -> h (reuses GH space)
  gemm_kernel<4><<<128 * 12, 256, 0, stream>>>(n2, wfc1, 16384, 1536, 384, 1536, fc1_b, nullptr, hbf, nullptr, nullptr);
  // fc2 + residual -> out
  gemm_kernel<3><<<128 * 3, 256, 0, stream>>>(hbf, wfc2, 16384, 384, 1536, 384, fc2_b, xmid, out, nullptr, nullptr);
}

// Round 5
// 363.910 us; speedup vs baseline: 1.2787x; 1.0635x over previous
//
#include <hip/hip_runtime.h>

typedef unsigned short u16;
typedef unsigned int u32;
typedef __attribute__((ext_vector_type(8))) short short8;
typedef __attribute__((ext_vector_type(4))) u16 u16x4;
typedef __attribute__((ext_vector_type(2))) u32 u32x2;
typedef __attribute__((ext_vector_type(4))) float f32x4;

__device__ __forceinline__ u16 f2bf(float f) {
  unsigned u = __float_as_uint(f);
  u += 0x7fffu + ((u >> 16) & 1u);
  return (u16)(u >> 16);
}

// async global->LDS DMA, 16B per lane, linear dest (wave-uniform base + lane*16)
#define GLD16(g, l)                                                        \
  __builtin_amdgcn_global_load_lds(                                        \
      (const __attribute__((address_space(1))) void*)(g),                  \
      (__attribute__((address_space(3))) void*)(l), 16, 0, 0)

// ---------------- transpose + cast weights: out[j*K+k] = in[(row0+k)*ld + j]
__global__ void transpose_cast_kernel(const float* __restrict__ in, int in_ld, int row0,
                                      u16* __restrict__ out, int K, int Nout) {
  int i = blockIdx.x * 256 + threadIdx.x;
  if (i >= K * Nout) return;
  int j = i / K, k = i - j * K;
  out[(size_t)j * K + k] = f2bf(in[(size_t)(row0 + k) * in_ld + j]);
}

// ---------------- LayerNorm: 1 wave per row of 384, 6 elems/lane
__global__ void ln_kernel(const float* __restrict__ in, const float* __restrict__ w,
                          const float* __restrict__ b, u16* __restrict__ out) {
  int row = blockIdx.x, t = threadIdx.x;
  const float* r = in + (size_t)row * 384;
  float v[6];
  float s = 0.f;
#pragma unroll
  for (int i = 0; i < 6; i++) { v[i] = r[t + 64 * i]; s += v[i]; }
#pragma unroll
  for (int off = 32; off > 0; off >>= 1) s += __shfl_xor(s, off);
  float mu = s * (1.f / 384.f);
  float q = 0.f;
#pragma unroll
  for (int i = 0; i < 6; i++) { float d = v[i] - mu; q += d * d; }
#pragma unroll
  for (int off = 32; off > 0; off >>= 1) q += __shfl_xor(q, off);
  float rstd = rsqrtf(q * (1.f / 384.f) + 1e-5f);
#pragma unroll
  for (int i = 0; i < 6; i++) {
    int j = t + 64 * i;
    out[(size_t)row * 384 + j] = f2bf((v[i] - mu) * rstd * w[j] + b[j]);
  }
}

// ---------------- bf16 MFMA GEMM: C[M,N] = A[M,K] * Bt[N,K]^T
// 128x128 tile, 256 thr (4 waves, 2x2), each wave 64x64 = 4x4 frags of 16x16x32.
// m97 recipe: global_load_lds dwordx4 staging into linear [128][32] LDS.
// Explicit s_waitcnt vmcnt(0) before the consumer barrier (T3 recipe; replay-race fix).
// MODE 0: f32 out            MODE 1: bf16 out + bias (strided ldc)
// MODE 2: qkv split (q scaled by 0.125*log2e, k bf16 [t,384]; v transposed [b][h][d][n])
// MODE 3: f32 out = acc + bias + res   MODE 4: bf16 out = gelu(acc+bias)
template <int MODE>
__global__ __launch_bounds__(256) void gemm_kernel(
    const u16* __restrict__ A, const u16* __restrict__ Bt,
    int M, int N, int K, int ldc,
    const float* __restrict__ bias, const float* __restrict__ res,
    void* __restrict__ out0, void* __restrict__ out1, void* __restrict__ out2) {
  __shared__ u16 Als[128 * 32];  // linear, no pad (global_load_lds dest)
  __shared__ u16 Bls[128 * 32];
  const int MB = M >> 7;
  int mb = blockIdx.x % MB, nb = blockIdx.x / MB;
  int m0 = mb << 7, n0 = nb << 7;
  int tid = threadIdx.x;
  int lane = tid & 63, w = tid >> 6;
  int wm = (w >> 1) << 6, wn = (w & 1) << 6;
  int l15 = lane & 15, l16 = lane >> 4;
  const f32x4 fz = {0.f, 0.f, 0.f, 0.f};
  f32x4 acc[4][4];
#pragma unroll
  for (int i = 0; i < 4; i++)
#pragma unroll
    for (int j = 0; j < 4; j++) acc[i][j] = fz;

  // staging: wave w covers tile rows [w*32, w*32+32); lane l -> row +(l>>2), chunk (l&3)*8
  const int strow = lane >> 2, stch = (lane & 3) * 8;
  const u16* Ag = A + (size_t)(m0 + w * 32 + strow) * K + stch;
  const u16* Bg = Bt + (size_t)(n0 + w * 32 + strow) * K + stch;
  u16* Al0 = &Als[(w * 32) * 32];
  u16* Bl0 = &Bls[(w * 32) * 32];

  for (int k0 = 0; k0 < K; k0 += 32) {
    __syncthreads();  // prev tile's ds_reads done
    GLD16(Ag + k0, Al0);
    GLD16(Ag + k0 + (size_t)16 * K, Al0 + 16 * 32);
    GLD16(Bg + k0, Bl0);
    GLD16(Bg + k0 + (size_t)16 * K, Bl0 + 16 * 32);
    asm volatile("s_waitcnt vmcnt(0)" ::: "memory");  // drain LDS-DMA before barrier
    __syncthreads();  // all waves' staging visible
    short8 af[4], bfr[4];
#pragma unroll
    for (int i = 0; i < 4; i++) {
      af[i]  = *(const short8*)&Als[(wm + i * 16 + l15) * 32 + l16 * 8];
      bfr[i] = *(const short8*)&Bls[(wn + i * 16 + l15) * 32 + l16 * 8];
    }
    __builtin_amdgcn_s_setprio(1);
#pragma unroll
    for (int i = 0; i < 4; i++)
#pragma unroll
      for (int j = 0; j < 4; j++)
        acc[i][j] = __builtin_amdgcn_mfma_f32_16x16x32_bf16(af[i], bfr[j], acc[i][j], 0, 0, 0);
    __builtin_amdgcn_s_setprio(0);
  }

#pragma unroll
  for (int i = 0; i < 4; i++)
#pragma unroll
    for (int j = 0; j < 4; j++)
#pragma unroll
      for (int r = 0; r < 4; r++) {
        int row = m0 + wm + i * 16 + l16 * 4 + r;
        int col = n0 + wn + j * 16 + l15;
        float v = acc[i][j][r];
        if (MODE == 0) {
          ((float*)out0)[(size_t)row * ldc + col] = v;
        } else if (MODE == 1) {
          ((u16*)out0)[(size_t)row * ldc + col] = f2bf(v + bias[col]);
        } else if (MODE == 2) {
          if (col < 384) {
            ((u16*)out0)[(size_t)row * 384 + col] = f2bf(v * 0.18033688011112042f);
          } else if (col < 768) {
            ((u16*)out1)[(size_t)row * 384 + col - 384] = f2bf(v);
          } else {
            int df = col - 768, hh = df >> 6, dd = df & 63;
            ((u16*)out2)[(((size_t)(row >> 11) * 6 + hh) * 64 + dd) * 2048 + (row & 2047)] = f2bf(v);
          }
        } else if (MODE == 3) {
          ((float*)out0)[(size_t)row * ldc + col] = v + bias[col] + res[(size_t)row * ldc + col];
        } else if (MODE == 4) {
          float u = v + bias[col];
          float g = 0.5f * u * (1.f + erff(u * 0.70710678118f));
          ((u16*)out0)[(size_t)row * ldc + col] = f2bf(g);
        }
      }
}

// ---------------- flash attention v3: swapped QK^T, defer-max, deferred lsum reduce
// grid = B*H*(N/64); 4 waves, 16 q per wave (q = l15), 64-key tiles
#define ASTR 80  // LDS row stride in u16 (160 B): 4-way max read conflicts, 16B-aligned
__global__ __launch_bounds__(256) void attn_kernel(const u16* __restrict__ qb,
                                                   const u16* __restrict__ kb,
                                                   const u16* __restrict__ vtb,
                                                   u16* __restrict__ ab) {
  __shared__ u16 Kls[64 * ASTR];
  __shared__ u16 Vls[64 * ASTR];   // [d][j] (V pre-transposed in global)
  __shared__ u16 Pls[64 * ASTR];   // P[q][key], per-wave 16-row slices
  int bx = blockIdx.x;
  int q0 = (bx & 31) << 6;
  int h = (bx >> 5) % 6;
  int b = bx / 192;
  int tid = threadIdx.x, lane = tid & 63, w = tid >> 6;
  int l15 = lane & 15, l16 = lane >> 4;

  // stage Q through Kls (freed before first K tile by the loop's first barrier)
  const size_t qbase = (size_t)(b * 2048 + q0) * 384 + h * 64;
  {
    int idx0 = tid, idx1 = 256 + tid;
    *(short8*)&Kls[(idx0 >> 3) * ASTR + (idx0 & 7) * 8] =
        *(const short8*)&qb[qbase + (size_t)(idx0 >> 3) * 384 + (idx0 & 7) * 8];
    *(short8*)&Kls[(idx1 >> 3) * ASTR + (idx1 & 7) * 8] =
        *(const short8*)&qb[qbase + (size_t)(idx1 >> 3) * 384 + (idx1 & 7) * 8];
  }
  __syncthreads();
  short8 aq0 = *(const short8*)&Kls[(w * 16 + l15) * ASTR + l16 * 8];
  short8 aq1 = *(const short8*)&Kls[(w * 16 + l15) * ASTR + 32 + l16 * 8];

  const f32x4 fz = {0.f, 0.f, 0.f, 0.f};
  f32x4 ot[4];  // O^T: lane q = l15; d = di*16 + l16*4 + r
#pragma unroll
  for (int di = 0; di < 4; di++) ot[di] = fz;
  float m = -1e30f, lpart = 0.f;  // lpart: per-lane partial sum (l16-quarter of keys)

  const size_t kbase = (size_t)b * 2048 * 384 + h * 64;
  const size_t vbase = ((size_t)b * 6 + h) * 64 * 2048;
  // staging: 64 rows x 64 cols = 512 short8 slots; 256 threads -> 2 slots each
  const int srow = tid >> 3, sch = (tid & 7) * 8;  // rows srow and srow+32

  // preload tile 0 into regs (T14-lite)
  short8 kr0 = *(const short8*)&kb[kbase + (size_t)srow * 384 + sch];
  short8 kr1 = *(const short8*)&kb[kbase + (size_t)(srow + 32) * 384 + sch];
  short8 vr0 = *(const short8*)&vtb[vbase + (size_t)srow * 2048 + sch];
  short8 vr1 = *(const short8*)&vtb[vbase + (size_t)(srow + 32) * 2048 + sch];

  for (int t = 0; t < 32; t++) {
    __syncthreads();  // previous tile's LDS reads done (and Q-staging consumed)
    *(short8*)&Kls[srow * ASTR + sch] = kr0;
    *(short8*)&Kls[(srow + 32) * ASTR + sch] = kr1;
    *(short8*)&Vls[srow * ASTR + sch] = vr0;
    *(short8*)&Vls[(srow + 32) * ASTR + sch] = vr1;
    if (t + 1 < 32) {  // issue next tile's loads; they fly during compute below
      int j0n = (t + 1) << 6;
      kr0 = *(const short8*)&kb[kbase + (size_t)(j0n + srow) * 384 + sch];
      kr1 = *(const short8*)&kb[kbase + (size_t)(j0n + srow + 32) * 384 + sch];
      vr0 = *(const short8*)&vtb[vbase + (size_t)srow * 2048 + j0n + sch];
      vr1 = *(const short8*)&vtb[vbase + (size_t)(srow + 32) * 2048 + j0n + sch];
    }
    __syncthreads();

    // S^T = K·Q^T : mfma(A=K_frag, B=Q_frag) -> col=q=l15, row=key
    f32x4 s[4];
    __builtin_amdgcn_s_setprio(1);
#pragma unroll
    for (int nj = 0; nj < 4; nj++) {
      short8 kf0 = *(const short8*)&Kls[(nj * 16 + l15) * ASTR + l16 * 8];
      short8 kf1 = *(const short8*)&Kls[(nj * 16 + l15) * ASTR + 32 + l16 * 8];
      s[nj] = __builtin_amdgcn_mfma_f32_16x16x32_bf16(kf0, aq0, fz, 0, 0, 0);
      s[nj] = __builtin_amdgcn_mfma_f32_16x16x32_bf16(kf1, aq1, s[nj], 0, 0, 0);
    }
    __builtin_amdgcn_s_setprio(0);

    // local max over this lane's 16 keys (max3-fusable chain), rescale only if grown
    float mloc = fmaxf(fmaxf(s[0][0], s[0][1]), s[0][2]);
    mloc = fmaxf(fmaxf(mloc, s[0][3]), s[1][0]);
    mloc = fmaxf(fmaxf(mloc, s[1][1]), s[1][2]);
    mloc = fmaxf(fmaxf(mloc, s[1][3]), s[2][0]);
    mloc = fmaxf(fmaxf(mloc, s[2][1]), s[2][2]);
    mloc = fmaxf(fmaxf(mloc, s[2][3]), s[3][0]);
    mloc = fmaxf(fmaxf(mloc, s[3][1]), s[3][2]);
    mloc = fmaxf(mloc, s[3][3]);
    if (__any(mloc > m)) {  // wave-uniform branch; rare after first tiles
      float mt = fmaxf(mloc, __shfl_xor(mloc, 16));
      mt = fmaxf(mt, __shfl_xor(mt, 32));
      float mn = fmaxf(m, mt);
      float alpha = exp2f(m - mn);
      m = mn;
      lpart *= alpha;
#pragma unroll
      for (int di = 0; di < 4; di++)
#pragma unroll
        for (int r = 0; r < 4; r++) ot[di][r] *= alpha;
    }

#pragma unroll
    for (int nj = 0; nj < 4; nj++) {
      float p0 = exp2f(s[nj][0] - m);
      float p1 = exp2f(s[nj][1] - m);
      float p2 = exp2f(s[nj][2] - m);
      float p3 = exp2f(s[nj][3] - m);
      lpart += (p0 + p1) + (p2 + p3);
      // truncate-pack to bf16 pairs (p in (0,1], trunc err < 0.4% rel)
      u32 lo = (__float_as_uint(p1) & 0xffff0000u) | (__float_as_uint(p0) >> 16);
      u32 hi = (__float_as_uint(p3) & 0xffff0000u) | (__float_as_uint(p2) >> 16);
      u32x2 pr = {lo, hi};
      *(u32x2*)&Pls[(w * 16 + l15) * ASTR + nj * 16 + l16 * 4] = pr;
    }

    // O^T += V^T · P^T : mfma(A=V^T_frag, B=P^T_frag) -> col=q=l15, row=d
    __builtin_amdgcn_s_setprio(1);
#pragma unroll
    for (int ks = 0; ks < 2; ks++) {
      short8 pb = *(const short8*)&Pls[(w * 16 + l15) * ASTR + ks * 32 + l16 * 8];
#pragma unroll
      for (int di = 0; di < 4; di++) {
        short8 vf = *(const short8*)&Vls[(di * 16 + l15) * ASTR + ks * 32 + l16 * 8];
        ot[di] = __builtin_amdgcn_mfma_f32_16x16x32_bf16(vf, pb, ot[di], 0, 0, 0);
      }
    }
    __builtin_amdgcn_s_setprio(0);
  }

  // final lsum reduce across the 4 l16 replicas (same q-row)
  lpart += __shfl_xor(lpart, 16);
  lpart += __shfl_xor(lpart, 32);
  float inv = 1.f / lpart;
  int token = b * 2048 + q0 + w * 16 + l15;
#pragma unroll
  for (int di = 0; di < 4; di++) {
    u16x4 pk4 = {f2bf(ot[di][0] * inv), f2bf(ot[di][1] * inv),
                 f2bf(ot[di][2] * inv), f2bf(ot[di][3] * inv)};
    *(u16x4*)&ab[(size_t)token * 384 + h * 64 + di * 16 + l16 * 4] = pk4;
  }
}

// ---------------- KNN: u = G[idx] + (H[n]-G[n]+b); max over 8; leaky; -> cat[:,384:768]
__global__ void knn_kernel(const float* __restrict__ GH, const int* __restrict__ kidx,
                           const float* __restrict__ kbias, u16* __restrict__ cat) {
  int f = blockIdx.x * 256 + threadIdx.x;
  if (f >= 16384 * 96) return;
  int token = f / 96, j4 = f - token * 96;
  int b = token >> 11, n = token & 2047;
  int j = j4 * 4;
  float4 gs = *(const float4*)&GH[(size_t)token * 768 + j];
  float4 hs = *(const float4*)&GH[(size_t)token * 768 + 384 + j];
  float4 kb4 = *(const float4*)&kbias[j];
  float dx = hs.x - gs.x + kb4.x, dy = hs.y - gs.y + kb4.y;
  float dz = hs.z - gs.z + kb4.z, dw = hs.w - gs.w + kb4.w;
  float mx = -1e30f, my = -1e30f, mz = -1e30f, mw = -1e30f;
#pragma unroll
  for (int k = 0; k < 8; k++) {
    int t = kidx[(b * 8 + k) * 2048 + n];
    float4 g = *(const float4*)&GH[(size_t)t * 768 + j];
    mx = fmaxf(mx, g.x + dx);
    my = fmaxf(my, g.y + dy);
    mz = fmaxf(mz, g.z + dz);
    mw = fmaxf(mw, g.w + dw);
  }
  mx = mx > 0.f ? mx : 0.2f * mx;
  my = my > 0.f ? my : 0.2f * my;
  mz = mz > 0.f ? mz : 0.2f * mz;
  mw = mw > 0.f ? mw : 0.2f * mw;
  u16x4 pk = {f2bf(mx), f2bf(my), f2bf(mz), f2bf(mw)};
  *(u16x4*)&cat[(size_t)token * 768 + 384 + j] = pk;
}

// ---------------- launch
extern "C" void kernel_launch(void* const* d_in, const int* in_sizes, int n_in,
                              void* d_out, int out_size, void* d_ws, size_t ws_size,
                              hipStream_t stream) {
  const float* x       = (const float*)d_in[0];
  const int*   kidx    = (const int*)d_in[1];
  const float* n1w     = (const float*)d_in[2];
  const float* n1b     = (const float*)d_in[3];
  const float* qkv_w   = (const float*)d_in[4];
  const float* proj_w  = (const float*)d_in[5];
  const float* proj_b  = (const float*)d_in[6];
  const float* knn_w   = (const float*)d_in[7];
  const float* knn_b   = (const float*)d_in[8];
  const float* merge_w = (const float*)d_in[9];
  const float* merge_b = (const float*)d_in[10];
  const float* n2w     = (const float*)d_in[11];
  const float* n2b     = (const float*)d_in[12];
  const float* fc1_w   = (const float*)d_in[13];
  const float* fc1_b   = (const float*)d_in[14];
  const float* fc2_w   = (const float*)d_in[15];
  const float* fc2_b   = (const float*)d_in[16];
  float* out = (float*)d_out;
  char* ws = (char*)d_ws;

  // ws layout (bytes) — with reuse, total ~130.5 MB
  u16* wqkv   = (u16*)(ws + 0);          // 1152x384 bf16
  u16* wproj  = (u16*)(ws + 884736);     // 384x384
  u16* wknn   = (u16*)(ws + 1179648);    // 768x384 (W1t | W2t)
  u16* wmerge = (u16*)(ws + 1769472);    // 384x768
  u16* wfc1   = (u16*)(ws + 2359296);    // 1536x384
  u16* wfc2   = (u16*)(ws + 3538944);    // 384x1536
  u16* nx     = (u16*)(ws + 4718592);    // norm_x bf16; later attn-out
  u16* qbf    = (u16*)(ws + 17301504);   // q (pre-scaled); later norm2 out
  u16* kbf    = (u16*)(ws + 29884416);   // k; later cat (spans k+vT)
  u16* vtb    = (u16*)(ws + 42467328);   // v transposed [b][h][d][n]
  float* GH   = (float*)(ws + 55050240); // [16384][768] f32; later h bf16
  float* xmid = (float*)(ws + 105381888);
  u16* cat = kbf;
  u16* n2  = qbf;
  u16* abf = nx;
  u16* hbf = (u16*)GH;

  // weight transposes (tiny)
  transpose_cast_kernel<<<(384 * 1152 + 255) / 256, 256, 0, stream>>>(qkv_w, 1152, 0, wqkv, 384, 1152);
  transpose_cast_kernel<<<(384 * 384 + 255) / 256, 256, 0, stream>>>(proj_w, 384, 0, wproj, 384, 384);
  transpose_cast_kernel<<<(384 * 384 + 255) / 256, 256, 0, stream>>>(knn_w, 384, 0, wknn, 384, 384);
  transpose_cast_kernel<<<(384 * 384 + 255) / 256, 256, 0, stream>>>(knn_w, 384, 384, wknn + 384 * 384, 384, 384);
  transpose_cast_kernel<<<(768 * 384 + 255) / 256, 256, 0, stream>>>(merge_w, 384, 0, wmerge, 768, 384);
  transpose_cast_kernel<<<(384 * 1536 + 255) / 256, 256, 0, stream>>>(fc1_w, 1536, 0, wfc1, 384, 1536);
  transpose_cast_kernel<<<(1536 * 384 + 255) / 256, 256, 0, stream>>>(fc2_w, 384, 0, wfc2, 1536, 384);

  // LN1
  ln_kernel<<<16384, 64, 0, stream>>>(x, n1w, n1b, nx);
  // qkv (split epilogue, q pre-scaled, v transposed)
  gemm_kernel<2><<<128 * 9, 256, 0, stream>>>(nx, wqkv, 16384, 1152, 384, 0, nullptr, nullptr, qbf, kbf, vtb);
  // GH = norm_x @ [W1|W2]
  gemm_kernel<0><<<128 * 6, 256, 0, stream>>>(nx, wknn, 16384, 768, 384, 768, nullptr, nullptr, GH, nullptr, nullptr);
  // attention -> abf (reuses nx space AFTER nx consumed)
  attn_kernel<<<1536, 256, 0, stream>>>(qbf, kbf, vtb, abf);
  // knn gather+max -> cat cols 384:768 (reuses k/v space AFTER attention)
  knn_kernel<<<6144, 256, 0, stream>>>(GH, kidx, knn_b, cat);
  // proj -> cat cols 0:384
  gemm_kernel<1><<<128 * 3, 256, 0, stream>>>(abf, wproj, 16384, 384, 384, 768, proj_b, nullptr, cat, nullptr, nullptr);
  // merge + residual -> xmid
  gemm_kernel<3><<<128 * 3, 256, 0, stream>>>(cat, wmerge, 16384, 384, 768, 384, merge_b, x, xmid, nullptr, nullptr);
  // LN2
  ln_kernel<<<16384, 64, 0, stream>>>(xmid, n2w, n2b, n2);
  // fc1 + gelu -> h (reuses GH space)
  gemm_kernel<4><<<128 * 12, 256, 0, stream>>>(n2, wfc1, 16384, 1536, 384, 1536, fc1_b, nullptr, hbf, nullptr, nullptr);
  // fc2 + residual -> out
  gemm_kernel<3><<<128 * 3, 256, 0, stream>>>(hbf, wfc2, 16384, 384, 1536, 384, fc2_b, xmid, out, nullptr, nullptr);
}